// Round 4
// baseline (443.397 us; speedup 1.0000x reference)
//
#include <hip/hip_runtime.h>
#include <math.h>

typedef unsigned short u16;
typedef unsigned int u32;

typedef float  floatx4 __attribute__((ext_vector_type(4)));
typedef short  shortx8 __attribute__((ext_vector_type(8)));

#define S_LEN 2048
#define E_DIM 1024
#define H_DIM 1024
#define V_DIM 32000

// d_out offsets (fp32 elements)
#define OUT_LOG 0
#define OUT_H   32000
#define OUT_C   33024
#define OUT_XT  34048
#define OUT_W   35072

// ws layout (floats)
#define WS_UB     0
#define WS_SCORES 1024
#define WS_CTX    3072
#define WS_MAXENC 4096
#define WS_MLZ    4097

__device__ __forceinline__ u16 f2bf(float f) {
    union { float f; u32 i; } v; v.f = f;
    u32 x = v.i;
    return (u16)((x + 0x7fffu + ((x >> 16) & 1u)) >> 16);
}
__device__ __forceinline__ u32 fenc(float f) {
    union { float f; u32 i; } v; v.f = f;
    return (v.i & 0x80000000u) ? ~v.i : (v.i | 0x80000000u);
}
__device__ __forceinline__ float fdec(u32 u) {
    union { u32 i; float f; } v;
    v.i = (u & 0x80000000u) ? (u ^ 0x80000000u) : ~u;
    return v.f;
}
__device__ __forceinline__ float wave_sum(float x) {
    #pragma unroll
    for (int m = 32; m >= 1; m >>= 1) x += __shfl_xor(x, m, 64);
    return x;
}
__device__ __forceinline__ float wave_max(float x) {
    #pragma unroll
    for (int m = 32; m >= 1; m >>= 1) x = fmaxf(x, __shfl_xor(x, m, 64));
    return x;
}

// ---------------- K1: LSTM cell -----------------------------------------
// grid 256 x 256: wave w handles hidden index j = blockIdx*4+w, rows
// {j, j+H, j+2H, j+3H} of gates = W_ih@[lc;emb] + b_ih + W_hh@h0 + b_hh
__global__ __launch_bounds__(256) void k_lstm(
    const float* __restrict__ last_ctx, const int* __restrict__ word,
    const float* __restrict__ emb, const float* __restrict__ h0,
    const float* __restrict__ c0,
    const float* __restrict__ W_ih, const float* __restrict__ b_ih,
    const float* __restrict__ W_hh, const float* __restrict__ b_hh,
    float* __restrict__ out_h, float* __restrict__ out_c)
{
    int tid = threadIdx.x;
    int w = tid >> 6, l = tid & 63;
    int j = blockIdx.x * 4 + w;

    int k0 = l * 32;   // cols [k0,k0+32) of 2048-wide lstm_in
    const float* src = (l < 32) ? (last_ctx + k0)
                                : (emb + (size_t)word[0] * E_DIM + (k0 - H_DIM));
    float sv[32];
    #pragma unroll
    for (int i = 0; i < 8; ++i) *(float4*)(sv + i * 4) = *(const float4*)(src + i * 4);

    int kh = l * 16;   // cols [kh,kh+16) of 1024-wide h0
    float hv[16];
    #pragma unroll
    for (int i = 0; i < 4; ++i) *(float4*)(hv + i * 4) = *(const float4*)(h0 + kh + i * 4);

    float gate[4];
    #pragma unroll
    for (int gt = 0; gt < 4; ++gt) {
        int row = gt * H_DIM + j;
        const float* wrow = W_ih + (size_t)row * (E_DIM + H_DIM) + k0;
        float s = 0.f;
        #pragma unroll
        for (int i = 0; i < 8; ++i) {
            float4 wv = *(const float4*)(wrow + i * 4);
            s += wv.x * sv[i*4+0] + wv.y * sv[i*4+1] + wv.z * sv[i*4+2] + wv.w * sv[i*4+3];
        }
        const float* hrow = W_hh + (size_t)row * H_DIM + kh;
        #pragma unroll
        for (int i = 0; i < 4; ++i) {
            float4 wv = *(const float4*)(hrow + i * 4);
            s += wv.x * hv[i*4+0] + wv.y * hv[i*4+1] + wv.z * hv[i*4+2] + wv.w * hv[i*4+3];
        }
        s = wave_sum(s);
        gate[gt] = s + b_ih[row] + b_hh[row];
    }
    if (l == 0) {
        float gi = 1.f / (1.f + expf(-gate[0]));
        float gf = 1.f / (1.f + expf(-gate[1]));
        float gg = tanhf(gate[2]);
        float go = 1.f / (1.f + expf(-gate[3]));
        float c = gf * c0[j] + gi * gg;
        float h = go * tanhf(c);
        out_h[j] = h;
        out_c[j] = c;
    }
}

// ---------------- K2: u[r] = b_att[r] + W_att[r,0:H] @ h; zero scratch ---
__global__ __launch_bounds__(256) void k_uproj(
    const float* __restrict__ W_att, const float* __restrict__ b_att,
    const float* __restrict__ out_h, float* __restrict__ wsf)
{
    int tid = threadIdx.x;
    int gid = blockIdx.x * 256 + tid;
    if (gid < S_LEN) wsf[WS_SCORES + gid] = 0.f;
    else if (gid < S_LEN + E_DIM) wsf[WS_CTX + gid - S_LEN] = 0.f;
    else if (gid == S_LEN + E_DIM) ((u32*)wsf)[WS_MAXENC] = 0u;

    int w = tid >> 6, l = tid & 63;
    int r = blockIdx.x * 4 + w;
    const float* wrow = W_att + (size_t)r * (E_DIM + H_DIM) + l * 16;
    const float* hp = out_h + l * 16;
    float s = 0.f;
    #pragma unroll
    for (int i = 0; i < 4; ++i) {
        float4 wv = *(const float4*)(wrow + i * 4);
        float4 hv = *(const float4*)(hp + i * 4);
        s += wv.x * hv.x + wv.y * hv.y + wv.z * hv.z + wv.w * hv.w;
    }
    s = wave_sum(s);
    if (l == 0) wsf[WS_UB + r] = s + b_att[r];
}

// ---------------- K3: fused scores GEMM ---------------------------------
// scores[s] = sum_r v[r] * tanh( ub[r] + sum_e enc[s,e]*W_att[r,H+e] )
// block: 4 waves = 64 s x 128 r tile; grid = 32 s-blocks x 8 r-blocks
#define LDS_P 40
__global__ __launch_bounds__(256) void k_att_scores(
    const float* __restrict__ enc, const float* __restrict__ W_att,
    const float* __restrict__ vvec, const float* __restrict__ ws_ub,
    float* __restrict__ ws_scores)
{
    __shared__ u16 lds_a[64 * LDS_P];    // enc tile: 64 s x 32 e (bf16)
    __shared__ u16 lds_b[128 * LDS_P];   // W tile: 128 r x 32 e (bf16)

    int tid = threadIdx.x;
    int w = tid >> 6, l = tid & 63;
    int b = blockIdx.x;
    int s0 = (b & 31) * 64;
    int r0 = (b >> 5) * 128;
    int lrow = l & 15, lq = l >> 4;

    floatx4 acc[8];
    #pragma unroll
    for (int i = 0; i < 8; ++i) acc[i] = (floatx4)0.f;

    int arow = tid >> 2, ac8 = (tid & 3) * 8;    // 64 rows x 4 thr, 8 floats each
    int brow = tid >> 1, bc16 = (tid & 1) * 16;  // 128 rows x 2 thr, 16 floats each

    for (int kc = 0; kc < 32; ++kc) {
        int e0 = kc * 32;
        __syncthreads();
        {
            const float* p = enc + (size_t)(s0 + arow) * E_DIM + e0 + ac8;
            float4 x = *(const float4*)p, y = *(const float4*)(p + 4);
            u16 tmp[8] = { f2bf(x.x), f2bf(x.y), f2bf(x.z), f2bf(x.w),
                           f2bf(y.x), f2bf(y.y), f2bf(y.z), f2bf(y.w) };
            *(uint4*)&lds_a[arow * LDS_P + ac8] = *(uint4*)tmp;
        }
        {
            const float* p = W_att + (size_t)(r0 + brow) * (E_DIM + H_DIM) + H_DIM + e0 + bc16;
            u16 tmp[16];
            #pragma unroll
            for (int m = 0; m < 16; m += 4) {
                float4 x = *(const float4*)(p + m);
                tmp[m] = f2bf(x.x); tmp[m+1] = f2bf(x.y);
                tmp[m+2] = f2bf(x.z); tmp[m+3] = f2bf(x.w);
            }
            *(uint4*)&lds_b[brow * LDS_P + bc16]     = *(uint4*)(tmp);
            *(uint4*)&lds_b[brow * LDS_P + bc16 + 8] = *(uint4*)(tmp + 8);
        }
        __syncthreads();

        shortx8 afrag = *(const shortx8*)&lds_a[(w * 16 + lrow) * LDS_P + lq * 8];
        #pragma unroll
        for (int rc = 0; rc < 8; ++rc) {
            shortx8 bfrag = *(const shortx8*)&lds_b[(rc * 16 + lrow) * LDS_P + lq * 8];
            acc[rc] = __builtin_amdgcn_mfma_f32_16x16x32_bf16(afrag, bfrag, acc[rc], 0, 0, 0);
        }
    }

    // C layout: col = lane&15 (r within 16), row = (lane>>4)*4 + reg (s within 16)
    float part[4] = {0.f, 0.f, 0.f, 0.f};
    #pragma unroll
    for (int rc = 0; rc < 8; ++rc) {
        int r = r0 + rc * 16 + lrow;
        float ubr = ws_ub[r];
        float vr  = vvec[r];
        #pragma unroll
        for (int reg = 0; reg < 4; ++reg)
            part[reg] += tanhf(acc[rc][reg] + ubr) * vr;
    }
    #pragma unroll
    for (int m = 1; m < 16; m <<= 1) {
        #pragma unroll
        for (int reg = 0; reg < 4; ++reg)
            part[reg] += __shfl_xor(part[reg], m, 64);
    }
    if (lrow == 0) {
        int sbase = s0 + w * 16 + lq * 4;
        #pragma unroll
        for (int reg = 0; reg < 4; ++reg)
            atomicAdd(&ws_scores[sbase + reg], part[reg]);
    }
}

// ---------------- K4: softmax over 2048 scores --------------------------
__global__ __launch_bounds__(1024) void k_softmax(
    const float* __restrict__ ws_scores, float* __restrict__ out_w)
{
    __shared__ float red[16];
    __shared__ float bmax, bsum;
    int tid = threadIdx.x;
    float s1 = ws_scores[tid], s2 = ws_scores[tid + 1024];
    float m = wave_max(fmaxf(s1, s2));
    if ((tid & 63) == 0) red[tid >> 6] = m;
    __syncthreads();
    if (tid == 0) {
        float mm = red[0];
        #pragma unroll
        for (int i = 1; i < 16; ++i) mm = fmaxf(mm, red[i]);
        bmax = mm;
    }
    __syncthreads();
    float M = bmax;
    float e1 = expf(s1 - M), e2 = expf(s2 - M);
    float s = wave_sum(e1 + e2);
    if ((tid & 63) == 0) red[tid >> 6] = s;
    __syncthreads();
    if (tid == 0) {
        float ss = 0.f;
        #pragma unroll
        for (int i = 0; i < 16; ++i) ss += red[i];
        bsum = ss;
    }
    __syncthreads();
    float inv = 1.f / bsum;
    out_w[tid] = e1 * inv; out_w[tid + 1024] = e2 * inv;
}

// ---------------- K5: context = w @ enc ---------------------------------
__global__ __launch_bounds__(256) void k_context(
    const float* __restrict__ enc, const float* __restrict__ out_w,
    float* __restrict__ ws_ctx)
{
    int tid = threadIdx.x, b = blockIdx.x;
    int e4 = tid * 4;
    int sbase = b * 32;
    float a0 = 0.f, a1 = 0.f, a2 = 0.f, a3 = 0.f;
    for (int i = 0; i < 32; ++i) {
        float wt = out_w[sbase + i];
        float4 ev = *(const float4*)(enc + (size_t)(sbase + i) * E_DIM + e4);
        a0 += wt * ev.x; a1 += wt * ev.y; a2 += wt * ev.z; a3 += wt * ev.w;
    }
    atomicAdd(&ws_ctx[e4 + 0], a0);
    atomicAdd(&ws_ctx[e4 + 1], a1);
    atomicAdd(&ws_ctx[e4 + 2], a2);
    atomicAdd(&ws_ctx[e4 + 3], a3);
}

// ---------------- K6: x_t = tanh(W_ah @ [ctx; h] + b_ah) ----------------
__global__ __launch_bounds__(256) void k_xt(
    const float* __restrict__ W_ah, const float* __restrict__ b_ah,
    const float* __restrict__ ws_ctx, const float* __restrict__ out_h,
    float* __restrict__ out_xt)
{
    int tid = threadIdx.x;
    int w = tid >> 6, l = tid & 63;
    int r = blockIdx.x * 4 + w;
    int k0 = l * 32;
    const float* wrow = W_ah + (size_t)r * (E_DIM + H_DIM) + k0;
    const float* src = (l < 32) ? (ws_ctx + k0) : (out_h + (k0 - E_DIM));
    float s = 0.f;
    #pragma unroll
    for (int i = 0; i < 8; ++i) {
        float4 wv = *(const float4*)(wrow + i * 4);
        float4 sv = *(const float4*)(src + i * 4);
        s += wv.x * sv.x + wv.y * sv.y + wv.z * sv.z + wv.w * sv.w;
    }
    s = wave_sum(s);
    if (l == 0) out_xt[r] = tanhf(s + b_ah[r]);
}

// ---------------- K7: logits to out_log (fp32) + global max -------------
__global__ __launch_bounds__(256) void k_logits(
    const float* __restrict__ W_out, const float* __restrict__ b_out,
    const float* __restrict__ out_xt,
    float* __restrict__ out_log, u32* __restrict__ ws_maxenc)
{
    __shared__ float wmax[4];
    int tid = threadIdx.x;
    int w = tid >> 6, l = tid & 63;
    int row = blockIdx.x * 4 + w;
    const float* wrow = W_out + (size_t)row * H_DIM + l * 16;
    const float* xp = out_xt + l * 16;
    float s = 0.f;
    #pragma unroll
    for (int i = 0; i < 4; ++i) {
        float4 wv = *(const float4*)(wrow + i * 4);
        float4 xv = *(const float4*)(xp + i * 4);
        s += wv.x * xv.x + wv.y * xv.y + wv.z * xv.z + wv.w * xv.w;
    }
    s = wave_sum(s);
    float lg = s + b_out[row];
    if (l == 0) { out_log[row] = lg; wmax[w] = lg; }
    __syncthreads();
    if (tid == 0) {
        float m = fmaxf(fmaxf(wmax[0], wmax[1]), fmaxf(wmax[2], wmax[3]));
        atomicMax(ws_maxenc, fenc(m));
    }
}

// ---------------- K8a: logZ = M + log(sum exp(logit - M)) ---------------
__global__ __launch_bounds__(1024) void k_lse(
    const float* __restrict__ out_log, const u32* __restrict__ ws_maxenc,
    float* __restrict__ ws_mlz)
{
    __shared__ float red[16];
    int tid = threadIdx.x;
    float M = fdec(ws_maxenc[0]);
    float s = 0.f;
    for (int i = tid; i < V_DIM; i += 1024) s += expf(out_log[i] - M);
    s = wave_sum(s);
    if ((tid & 63) == 0) red[tid >> 6] = s;
    __syncthreads();
    if (tid == 0) {
        float ss = 0.f;
        #pragma unroll
        for (int i = 0; i < 16; ++i) ss += red[i];
        ws_mlz[0] = M + logf(ss);
    }
}

// ---------------- K8b: out_log -= logZ; copy ctx is not needed ----------
__global__ __launch_bounds__(256) void k_writeout(
    const float* __restrict__ ws_mlz, float* __restrict__ out_log)
{
    int i = blockIdx.x * 256 + threadIdx.x;
    out_log[i] = out_log[i] - ws_mlz[0];
}

extern "C" void kernel_launch(void* const* d_in, const int* in_sizes, int n_in,
                              void* d_out, int out_size, void* d_ws, size_t ws_size,
                              hipStream_t stream) {
    const float* enc      = (const float*)d_in[0];
    const int*   word     = (const int*)d_in[1];
    const float* last_ctx = (const float*)d_in[2];
    const float* h0       = (const float*)d_in[3];
    const float* c0       = (const float*)d_in[4];
    const float* emb      = (const float*)d_in[5];
    const float* W_ih     = (const float*)d_in[6];
    const float* b_ih     = (const float*)d_in[7];
    const float* W_hh     = (const float*)d_in[8];
    const float* b_hh     = (const float*)d_in[9];
    const float* W_att    = (const float*)d_in[10];
    const float* b_att    = (const float*)d_in[11];
    const float* vvec     = (const float*)d_in[12];
    const float* W_ah     = (const float*)d_in[13];
    const float* b_ah     = (const float*)d_in[14];
    const float* W_out    = (const float*)d_in[15];
    const float* b_out    = (const float*)d_in[16];

    float* wsf = (float*)d_ws;

    float* out     = (float*)d_out;
    float* out_log = out + OUT_LOG;
    float* out_h   = out + OUT_H;
    float* out_c   = out + OUT_C;
    float* out_xt  = out + OUT_XT;
    float* out_w   = out + OUT_W;

    k_lstm<<<256, 256, 0, stream>>>(last_ctx, word, emb, h0, c0,
                                    W_ih, b_ih, W_hh, b_hh, out_h, out_c);
    k_uproj<<<256, 256, 0, stream>>>(W_att, b_att, out_h, wsf);
    k_att_scores<<<256, 256, 0, stream>>>(enc, W_att, vvec,
                                          wsf + WS_UB, wsf + WS_SCORES);
    k_softmax<<<1, 1024, 0, stream>>>(wsf + WS_SCORES, out_w);
    k_context<<<64, 256, 0, stream>>>(enc, out_w, wsf + WS_CTX);
    k_xt<<<256, 256, 0, stream>>>(W_ah, b_ah, wsf + WS_CTX, out_h, out_xt);
    k_logits<<<8000, 256, 0, stream>>>(W_out, b_out, out_xt,
                                       out_log, (u32*)wsf + WS_MAXENC);
    k_lse<<<1, 1024, 0, stream>>>(out_log, (u32*)wsf + WS_MAXENC, wsf + WS_MLZ);
    k_writeout<<<125, 256, 0, stream>>>(wsf + WS_MLZ, out_log);
}

// Round 5
// 401.425 us; speedup vs baseline: 1.1046x; 1.1046x over previous
//
#include <hip/hip_runtime.h>
#include <math.h>

typedef unsigned short u16;
typedef unsigned int u32;

typedef float  floatx4 __attribute__((ext_vector_type(4)));
typedef short  shortx8 __attribute__((ext_vector_type(8)));

#define S_LEN 2048
#define E_DIM 1024
#define H_DIM 1024
#define V_DIM 32000

// d_out offsets (fp32 elements)
#define OUT_LOG 0
#define OUT_H   32000
#define OUT_C   33024
#define OUT_XT  34048
#define OUT_W   35072

// ws layout (floats)
#define WS_UB     0
#define WS_SCORES 1024
#define WS_CTX    3072
#define WS_MAXENC 4096
#define WS_EXPSUM 4097

__device__ __forceinline__ u16 f2bf_fast(float f) {
    union { float f; u32 i; } v; v.f = f;
    return (u16)((v.i + 0x8000u) >> 16);
}
__device__ __forceinline__ u32 fenc(float f) {
    union { float f; u32 i; } v; v.f = f;
    return (v.i & 0x80000000u) ? ~v.i : (v.i | 0x80000000u);
}
__device__ __forceinline__ float fdec(u32 u) {
    union { u32 i; float f; } v;
    v.i = (u & 0x80000000u) ? (u ^ 0x80000000u) : ~u;
    return v.f;
}
__device__ __forceinline__ float red16_sum(float x) {
    #pragma unroll
    for (int m = 1; m <= 8; m <<= 1) x += __shfl_xor(x, m, 64);
    return x;
}
__device__ __forceinline__ float wave_sum(float x) {
    #pragma unroll
    for (int m = 32; m >= 1; m >>= 1) x += __shfl_xor(x, m, 64);
    return x;
}
__device__ __forceinline__ float wave_max(float x) {
    #pragma unroll
    for (int m = 32; m >= 1; m >>= 1) x = fmaxf(x, __shfl_xor(x, m, 64));
    return x;
}
__device__ __forceinline__ float dot4(float4 a, float4 b) {
    return a.x * b.x + a.y * b.y + a.z * b.z + a.w * b.w;
}

// ---------------- K1: LSTM cell -----------------------------------------
// wave = one hidden unit j; lane group g=l>>4 computes gate-row g*H+j with
// 16-lane contiguous float4 loads. Grid 256 x 256 (4 hidden/block).
__global__ __launch_bounds__(256) void k_lstm(
    const float* __restrict__ last_ctx, const int* __restrict__ word,
    const float* __restrict__ emb, const float* __restrict__ h0,
    const float* __restrict__ c0,
    const float* __restrict__ W_ih, const float* __restrict__ b_ih,
    const float* __restrict__ W_hh, const float* __restrict__ b_hh,
    float* __restrict__ out_h, float* __restrict__ out_c)
{
    int tid = threadIdx.x;
    int w = tid >> 6, l = tid & 63;
    int g = l >> 4, l16 = l & 15;
    int j = blockIdx.x * 4 + w;
    int row = g * H_DIM + j;
    const float* embrow = emb + (size_t)word[0] * E_DIM;
    const float* wrow = W_ih + (size_t)row * (E_DIM + H_DIM);
    const float* hrow = W_hh + (size_t)row * H_DIM;
    int c4 = l16 * 4;

    float s = 0.f;
    #pragma unroll 4
    for (int it = 0; it < 16; ++it) {           // lstm_in cols [0,1024): last_ctx
        int col = it * 64 + c4;
        s += dot4(*(const float4*)(wrow + col), *(const float4*)(last_ctx + col));
    }
    #pragma unroll 4
    for (int it = 0; it < 16; ++it) {           // lstm_in cols [1024,2048): emb
        int col = it * 64 + c4;
        s += dot4(*(const float4*)(wrow + 1024 + col), *(const float4*)(embrow + col));
    }
    #pragma unroll 4
    for (int it = 0; it < 16; ++it) {           // W_hh @ h0
        int col = it * 64 + c4;
        s += dot4(*(const float4*)(hrow + col), *(const float4*)(h0 + col));
    }
    s = red16_sum(s);
    if (l16 == 0) s += b_ih[row] + b_hh[row];
    float g0 = __shfl(s, 0,  64);
    float g1 = __shfl(s, 16, 64);
    float g2 = __shfl(s, 32, 64);
    float g3 = __shfl(s, 48, 64);
    if (l == 0) {
        float gi = 1.f / (1.f + expf(-g0));
        float gf = 1.f / (1.f + expf(-g1));
        float gg = tanhf(g2);
        float go = 1.f / (1.f + expf(-g3));
        float c = gf * c0[j] + gi * gg;
        float h = go * tanhf(c);
        out_h[j] = h;
        out_c[j] = c;
    }
}

// ---------------- K2: u[r] = b_att[r] + W_att[r,0:H] @ h; zero scratch ---
// wave = 4 rows; grid 64 x 256 (16 rows/block)
__global__ __launch_bounds__(256) void k_uproj(
    const float* __restrict__ W_att, const float* __restrict__ b_att,
    const float* __restrict__ out_h, float* __restrict__ wsf)
{
    int tid = threadIdx.x;
    int gid = blockIdx.x * 256 + tid;
    if (gid < S_LEN) wsf[WS_SCORES + gid] = 0.f;
    else if (gid < S_LEN + E_DIM) wsf[WS_CTX + gid - S_LEN] = 0.f;
    else if (gid == S_LEN + E_DIM) ((u32*)wsf)[WS_MAXENC] = 0u;
    else if (gid == S_LEN + E_DIM + 1) wsf[WS_EXPSUM] = 0.f;

    int w = tid >> 6, l = tid & 63;
    int sub = l >> 4, l16 = l & 15;
    int r = blockIdx.x * 16 + w * 4 + sub;
    const float* wrow = W_att + (size_t)r * (E_DIM + H_DIM);
    int c4 = l16 * 4;
    float s = 0.f;
    #pragma unroll 4
    for (int it = 0; it < 16; ++it) {
        int col = it * 64 + c4;
        s += dot4(*(const float4*)(wrow + col), *(const float4*)(out_h + col));
    }
    s = red16_sum(s);
    if (l16 == 0) wsf[WS_UB + r] = s + b_att[r];
}

// ---------------- K3: fused scores GEMM ---------------------------------
// scores[s] = sum_r v[r] * tanh( ub[r] + sum_e enc[s,e]*W_att[r,H+e] )
// tile 128s x 128r; grid = 16 s-blocks x 8 r-blocks = 128 blocks
#define LDS_P 40
__global__ __launch_bounds__(256) void k_att_scores(
    const float* __restrict__ enc, const float* __restrict__ W_att,
    const float* __restrict__ vvec, const float* __restrict__ ws_ub,
    float* __restrict__ ws_scores)
{
    __shared__ u16 lds_a[128 * LDS_P];   // enc tile: 128 s x 32 e (bf16)
    __shared__ u16 lds_b[128 * LDS_P];   // W tile: 128 r x 32 e (bf16)

    int tid = threadIdx.x;
    int w = tid >> 6, l = tid & 63;
    int b = blockIdx.x;
    int s0 = (b & 15) * 128;
    int r0 = (b >> 4) * 128;
    int lrow = l & 15, lq = l >> 4;

    floatx4 acc[2][8];
    #pragma unroll
    for (int sf = 0; sf < 2; ++sf)
        #pragma unroll
        for (int i = 0; i < 8; ++i) acc[sf][i] = (floatx4)0.f;

    int srow = tid >> 1, scol = (tid & 1) * 16;  // staging: 128 rows x 2 thr

    for (int kc = 0; kc < 32; ++kc) {
        int e0 = kc * 32;
        __syncthreads();
        {
            const float* p = enc + (size_t)(s0 + srow) * E_DIM + e0 + scol;
            u16 tmp[16];
            #pragma unroll
            for (int m = 0; m < 16; m += 4) {
                float4 x = *(const float4*)(p + m);
                tmp[m] = f2bf_fast(x.x); tmp[m+1] = f2bf_fast(x.y);
                tmp[m+2] = f2bf_fast(x.z); tmp[m+3] = f2bf_fast(x.w);
            }
            *(uint4*)&lds_a[srow * LDS_P + scol]     = *(uint4*)(tmp);
            *(uint4*)&lds_a[srow * LDS_P + scol + 8] = *(uint4*)(tmp + 8);
        }
        {
            const float* p = W_att + (size_t)(r0 + srow) * (E_DIM + H_DIM) + H_DIM + e0 + scol;
            u16 tmp[16];
            #pragma unroll
            for (int m = 0; m < 16; m += 4) {
                float4 x = *(const float4*)(p + m);
                tmp[m] = f2bf_fast(x.x); tmp[m+1] = f2bf_fast(x.y);
                tmp[m+2] = f2bf_fast(x.z); tmp[m+3] = f2bf_fast(x.w);
            }
            *(uint4*)&lds_b[srow * LDS_P + scol]     = *(uint4*)(tmp);
            *(uint4*)&lds_b[srow * LDS_P + scol + 8] = *(uint4*)(tmp + 8);
        }
        __syncthreads();

        shortx8 afrag[2];
        afrag[0] = *(const shortx8*)&lds_a[(w * 32 + lrow) * LDS_P + lq * 8];
        afrag[1] = *(const shortx8*)&lds_a[(w * 32 + 16 + lrow) * LDS_P + lq * 8];
        #pragma unroll
        for (int rc = 0; rc < 8; ++rc) {
            shortx8 bfrag = *(const shortx8*)&lds_b[(rc * 16 + lrow) * LDS_P + lq * 8];
            acc[0][rc] = __builtin_amdgcn_mfma_f32_16x16x32_bf16(afrag[0], bfrag, acc[0][rc], 0, 0, 0);
            acc[1][rc] = __builtin_amdgcn_mfma_f32_16x16x32_bf16(afrag[1], bfrag, acc[1][rc], 0, 0, 0);
        }
    }

    // C layout: col = lane&15 (r), row = (lane>>4)*4 + reg (s)
    float part[2][4] = {{0.f,0.f,0.f,0.f},{0.f,0.f,0.f,0.f}};
    #pragma unroll
    for (int rc = 0; rc < 8; ++rc) {
        int r = r0 + rc * 16 + lrow;
        float ubr = ws_ub[r];
        float vr  = vvec[r];
        #pragma unroll
        for (int sf = 0; sf < 2; ++sf)
            #pragma unroll
            for (int reg = 0; reg < 4; ++reg)
                part[sf][reg] += tanhf(acc[sf][rc][reg] + ubr) * vr;
    }
    #pragma unroll
    for (int m = 1; m <= 8; m <<= 1)
        #pragma unroll
        for (int sf = 0; sf < 2; ++sf)
            #pragma unroll
            for (int reg = 0; reg < 4; ++reg)
                part[sf][reg] += __shfl_xor(part[sf][reg], m, 64);
    if (lrow == 0) {
        #pragma unroll
        for (int sf = 0; sf < 2; ++sf) {
            int sbase = s0 + w * 32 + sf * 16 + lq * 4;
            #pragma unroll
            for (int reg = 0; reg < 4; ++reg)
                atomicAdd(&ws_scores[sbase + reg], part[sf][reg]);
        }
    }
}

// ---------------- K4: softmax over 2048 scores --------------------------
__global__ __launch_bounds__(1024) void k_softmax(
    const float* __restrict__ ws_scores, float* __restrict__ out_w)
{
    __shared__ float red[16];
    __shared__ float bmax, bsum;
    int tid = threadIdx.x;
    float s1 = ws_scores[tid], s2 = ws_scores[tid + 1024];
    float m = wave_max(fmaxf(s1, s2));
    if ((tid & 63) == 0) red[tid >> 6] = m;
    __syncthreads();
    if (tid == 0) {
        float mm = red[0];
        #pragma unroll
        for (int i = 1; i < 16; ++i) mm = fmaxf(mm, red[i]);
        bmax = mm;
    }
    __syncthreads();
    float M = bmax;
    float e1 = expf(s1 - M), e2 = expf(s2 - M);
    float s = wave_sum(e1 + e2);
    if ((tid & 63) == 0) red[tid >> 6] = s;
    __syncthreads();
    if (tid == 0) {
        float ss = 0.f;
        #pragma unroll
        for (int i = 0; i < 16; ++i) ss += red[i];
        bsum = ss;
    }
    __syncthreads();
    float inv = 1.f / bsum;
    out_w[tid] = e1 * inv; out_w[tid + 1024] = e2 * inv;
}

// ---------------- K5: context = w @ enc ---------------------------------
// grid 128: block b covers s in [b*16, b*16+16); thread t covers e=4t..4t+3
__global__ __launch_bounds__(256) void k_context(
    const float* __restrict__ enc, const float* __restrict__ out_w,
    float* __restrict__ ws_ctx)
{
    int tid = threadIdx.x, b = blockIdx.x;
    int e4 = tid * 4;
    int sbase = b * 16;
    float a0 = 0.f, a1 = 0.f, a2 = 0.f, a3 = 0.f;
    #pragma unroll 4
    for (int i = 0; i < 16; ++i) {
        float wt = out_w[sbase + i];
        float4 ev = *(const float4*)(enc + (size_t)(sbase + i) * E_DIM + e4);
        a0 += wt * ev.x; a1 += wt * ev.y; a2 += wt * ev.z; a3 += wt * ev.w;
    }
    atomicAdd(&ws_ctx[e4 + 0], a0);
    atomicAdd(&ws_ctx[e4 + 1], a1);
    atomicAdd(&ws_ctx[e4 + 2], a2);
    atomicAdd(&ws_ctx[e4 + 3], a3);
}

// ---------------- K6: x_t = tanh(W_ah @ [ctx; h] + b_ah) ----------------
// wave = 4 rows; grid 64 x 256
__global__ __launch_bounds__(256) void k_xt(
    const float* __restrict__ W_ah, const float* __restrict__ b_ah,
    const float* __restrict__ ws_ctx, const float* __restrict__ out_h,
    float* __restrict__ out_xt)
{
    int tid = threadIdx.x;
    int w = tid >> 6, l = tid & 63;
    int sub = l >> 4, l16 = l & 15;
    int r = blockIdx.x * 16 + w * 4 + sub;
    const float* wrow = W_ah + (size_t)r * (E_DIM + H_DIM);
    int c4 = l16 * 4;
    float s = 0.f;
    #pragma unroll 4
    for (int it = 0; it < 16; ++it) {       // ctx part
        int col = it * 64 + c4;
        s += dot4(*(const float4*)(wrow + col), *(const float4*)(ws_ctx + col));
    }
    #pragma unroll 4
    for (int it = 0; it < 16; ++it) {       // h part
        int col = it * 64 + c4;
        s += dot4(*(const float4*)(wrow + 1024 + col), *(const float4*)(out_h + col));
    }
    s = red16_sum(s);
    if (l16 == 0) out_xt[r] = tanhf(s + b_ah[r]);
}

// ---------------- K7: logits + global max -------------------------------
// wave = 4 rows; grid 2000 x 256 (16 rows/block)
__global__ __launch_bounds__(256) void k_logits(
    const float* __restrict__ W_out, const float* __restrict__ b_out,
    const float* __restrict__ out_xt,
    float* __restrict__ out_log, u32* __restrict__ ws_maxenc)
{
    __shared__ float wmax[4];
    int tid = threadIdx.x;
    int w = tid >> 6, l = tid & 63;
    int sub = l >> 4, l16 = l & 15;
    int row = blockIdx.x * 16 + w * 4 + sub;
    const float* wrow = W_out + (size_t)row * H_DIM;
    int c4 = l16 * 4;
    float s = 0.f;
    #pragma unroll 4
    for (int it = 0; it < 16; ++it) {
        int col = it * 64 + c4;
        s += dot4(*(const float4*)(wrow + col), *(const float4*)(out_xt + col));
    }
    s = red16_sum(s);
    float lg = s + b_out[row];
    float wm = -1e30f;
    if (l16 == 0) { out_log[row] = lg; wm = lg; }
    wm = wave_max(wm);
    if (l == 0) wmax[w] = wm;
    __syncthreads();
    if (tid == 0) {
        float m = fmaxf(fmaxf(wmax[0], wmax[1]), fmaxf(wmax[2], wmax[3]));
        atomicMax(ws_maxenc, fenc(m));
    }
}

// ---------------- K8a: partial sum of exp(logit - M) --------------------
// grid 125 x 256, one elem per thread, atomicAdd block partials
__global__ __launch_bounds__(256) void k_lse(
    const float* __restrict__ out_log, const u32* __restrict__ ws_maxenc,
    float* __restrict__ ws_expsum)
{
    __shared__ float red[4];
    int tid = threadIdx.x;
    int i = blockIdx.x * 256 + tid;
    float M = fdec(ws_maxenc[0]);
    float s = expf(out_log[i] - M);
    s = wave_sum(s);
    if ((tid & 63) == 0) red[tid >> 6] = s;
    __syncthreads();
    if (tid == 0)
        atomicAdd(ws_expsum, red[0] + red[1] + red[2] + red[3]);
}

// ---------------- K8b: out_log -= M + log(expsum) -----------------------
__global__ __launch_bounds__(256) void k_writeout(
    const u32* __restrict__ ws_maxenc, const float* __restrict__ ws_expsum,
    float* __restrict__ out_log)
{
    int i = blockIdx.x * 256 + threadIdx.x;
    float lz = fdec(ws_maxenc[0]) + logf(ws_expsum[0]);
    out_log[i] = out_log[i] - lz;
}

extern "C" void kernel_launch(void* const* d_in, const int* in_sizes, int n_in,
                              void* d_out, int out_size, void* d_ws, size_t ws_size,
                              hipStream_t stream) {
    const float* enc      = (const float*)d_in[0];
    const int*   word     = (const int*)d_in[1];
    const float* last_ctx = (const float*)d_in[2];
    const float* h0       = (const float*)d_in[3];
    const float* c0       = (const float*)d_in[4];
    const float* emb      = (const float*)d_in[5];
    const float* W_ih     = (const float*)d_in[6];
    const float* b_ih     = (const float*)d_in[7];
    const float* W_hh     = (const float*)d_in[8];
    const float* b_hh     = (const float*)d_in[9];
    const float* W_att    = (const float*)d_in[10];
    const float* b_att    = (const float*)d_in[11];
    const float* vvec     = (const float*)d_in[12];
    const float* W_ah     = (const float*)d_in[13];
    const float* b_ah     = (const float*)d_in[14];
    const float* W_out    = (const float*)d_in[15];
    const float* b_out    = (const float*)d_in[16];

    float* wsf = (float*)d_ws;

    float* out     = (float*)d_out;
    float* out_log = out + OUT_LOG;
    float* out_h   = out + OUT_H;
    float* out_c   = out + OUT_C;
    float* out_xt  = out + OUT_XT;
    float* out_w   = out + OUT_W;

    k_lstm<<<256, 256, 0, stream>>>(last_ctx, word, emb, h0, c0,
                                    W_ih, b_ih, W_hh, b_hh, out_h, out_c);
    k_uproj<<<64, 256, 0, stream>>>(W_att, b_att, out_h, wsf);
    k_att_scores<<<128, 256, 0, stream>>>(enc, W_att, vvec,
                                          wsf + WS_UB, wsf + WS_SCORES);
    k_softmax<<<1, 1024, 0, stream>>>(wsf + WS_SCORES, out_w);
    k_context<<<128, 256, 0, stream>>>(enc, out_w, wsf + WS_CTX);
    k_xt<<<64, 256, 0, stream>>>(W_ah, b_ah, wsf + WS_CTX, out_h, out_xt);
    k_logits<<<2000, 256, 0, stream>>>(W_out, b_out, out_xt,
                                       out_log, (u32*)wsf + WS_MAXENC);
    k_lse<<<125, 256, 0, stream>>>(out_log, (u32*)wsf + WS_MAXENC,
                                   wsf + WS_EXPSUM);
    k_writeout<<<125, 256, 0, stream>>>((u32*)wsf + WS_MAXENC,
                                        wsf + WS_EXPSUM, out_log);
}